// Round 5
// baseline (119.318 us; speedup 1.0000x reference)
//
#include <hip/hip_runtime.h>

// B=2, HEADS=8, T=8, QH=QW=16, D=64; rows = 32768, K = 2048.
// out[row, k] = scores[row, k] + dotH(qh,kh) + dotW(qw,kw) + dotT(t,kt)
// k = kt*256 + kh*16 + kw; row = (b*H+n)*2048 + t*256 + qh*16 + qw.
//
// v5: persistent-shaped. 1024 blocks x 4 waves; each wave owns 8 consecutive
// rows. Double-buffered row pipeline: issue row r+1's 8 stream loads before
// flushing row r, so each wave keeps >=8 HBM loads in flight continuously
// (counted-vmcnt pattern, never drains to 0 mid-stream). Biases are computed
// one row ahead, broadcast via __shfl (no LDS, no barriers).

typedef float v4f __attribute__((ext_vector_type(4)));

#define WAVES 4
#define RPW   8   // rows per wave

__global__ __launch_bounds__(256) void relpos_fused_v5(
    const float* __restrict__ query,   // [32768, 64]
    const float* __restrict__ scores,  // [32768, 2048]
    const float* __restrict__ hemb,    // [31, 64]
    const float* __restrict__ wemb,    // [31, 64]
    const float* __restrict__ temb,    // [15, 64]
    float* __restrict__ out)           // [32768, 2048]
{
    const int tid  = threadIdx.x;
    const int wv   = tid >> 6;
    const int lane = tid & 63;
    const int r0   = (blockIdx.x * WAVES + wv) * RPW;

    // Per-lane broadcast sources: element = i*256 + lane*4 + c
    //   kt = i, kh = lane>>2, kw = (lane&3)*4 + c
    const int hsrc = lane >> 2;            // lane holding biasH[kh]
    const int wsrc = 16 + (lane & 3) * 4;  // first lane of biasW quad

    auto issue_loads = [&](int grow, v4f (&buf)[8]) {
        const v4f* sp = (const v4f*)scores + (size_t)grow * 512 + lane;
        #pragma unroll
        for (int i = 0; i < 8; ++i)
            buf[i] = __builtin_nontemporal_load(&sp[i * 64]);
    };

    auto compute_bias = [&](int grow, v4f& hw4, float (&tv)[8]) {
        const int row = grow & 2047;
        const int tt  = row >> 8;
        const int qh  = (row >> 4) & 15;
        const int qw  = row & 15;
        float acc = 0.f;
        if (lane < 40) {
            const float* emb;
            int eidx;
            if (lane < 16)      { emb = hemb; eidx = qh - lane + 15; }
            else if (lane < 32) { emb = wemb; eidx = qw - (lane - 16) + 15; }
            else                { emb = temb; eidx = tt - (lane - 32) + 7; }
            const v4f* e4 = (const v4f*)(emb + eidx * 64);
            const v4f* q4 = (const v4f*)(query + (size_t)grow * 64);
            v4f a4 = (v4f)(0.f);
            #pragma unroll
            for (int k = 0; k < 16; ++k) a4 += q4[k] * e4[k];
            acc = (a4.x + a4.y) + (a4.z + a4.w);
        }
        const float h = __shfl(acc, hsrc, 64);
        v4f w;
        w.x = __shfl(acc, wsrc + 0, 64);
        w.y = __shfl(acc, wsrc + 1, 64);
        w.z = __shfl(acc, wsrc + 2, 64);
        w.w = __shfl(acc, wsrc + 3, 64);
        hw4 = w + h;
        #pragma unroll
        for (int i = 0; i < 8; ++i) tv[i] = __shfl(acc, 32 + i, 64);
    };

    auto flush = [&](int grow, const v4f (&buf)[8], const v4f& hw4,
                     const float (&tv)[8]) {
        v4f* op = (v4f*)out + (size_t)grow * 512 + lane;
        #pragma unroll
        for (int i = 0; i < 8; ++i) {
            v4f o = buf[i] + hw4 + tv[i];
            __builtin_nontemporal_store(o, &op[i * 64]);
        }
    };

    v4f   bufA[8], bufB[8];
    v4f   hwA, hwB;
    float tvA[8], tvB[8];

    // Prologue: row 0 of this wave.
    issue_loads(r0, bufA);
    compute_bias(r0, hwA, tvA);

    #pragma unroll
    for (int rr = 0; rr < RPW; rr += 2) {
        // Issue row rr+1's stream loads BEFORE flushing row rr: the flush's
        // vmcnt wait leaves B's loads in flight (counted, not drained).
        issue_loads(r0 + rr + 1, bufB);
        compute_bias(r0 + rr + 1, hwB, tvB);
        flush(r0 + rr, bufA, hwA, tvA);

        if (rr + 2 < RPW) {
            issue_loads(r0 + rr + 2, bufA);
            compute_bias(r0 + rr + 2, hwA, tvA);
        }
        flush(r0 + rr + 1, bufB, hwB, tvB);
    }
}

extern "C" void kernel_launch(void* const* d_in, const int* in_sizes, int n_in,
                              void* d_out, int out_size, void* d_ws, size_t ws_size,
                              hipStream_t stream) {
    const float* query  = (const float*)d_in[0];
    const float* scores = (const float*)d_in[1];
    const float* hemb   = (const float*)d_in[2];
    const float* wemb   = (const float*)d_in[3];
    const float* temb   = (const float*)d_in[4];
    float* out = (float*)d_out;

    relpos_fused_v5<<<32768 / (WAVES * RPW), 256, 0, stream>>>(
        query, scores, hemb, wemb, temb, out);
}